// Round 18
// baseline (684.718 us; speedup 1.0000x reference)
//
#include <hip/hip_runtime.h>

// ---------------------------------------------------------------------------
// DbrxAttention on MI355X (gfx950).
// gemm1: 256x256, BK=64, dbuf LDS, relaxed 4-phase schedule, XOR-8 swizzle,
//   setprio (~904 TF; 8-phase transplants tested rounds 5/6/9/16 - all <=).
// gemm2: 128x192, 80 KB LDS -> 2 blocks/CU (round-15 winner).
// Attention: 4-wave blocks, K LDS-staged (swizzled, dbuf), V^T read DIRECT
//   from global (L2-hot, m169: don't stage L2-fit data), swapped-QK^T
//   32x32x16, softmax in registers (exp2 domain), reversed bx.
// wtrans: 64kx32n tile, float4 reads + bf16x8 writes.
// ---------------------------------------------------------------------------

#define S_   2048
#define D_   6144
#define H_   48
#define KV_  8
#define HD_  128
#define NQK  8192
#define REP  6

typedef __attribute__((ext_vector_type(8)))  __bf16 bf16x8;
typedef __attribute__((ext_vector_type(4)))  __bf16 bf16x4;
typedef __attribute__((ext_vector_type(2)))  __bf16 bf16x2;
typedef __attribute__((ext_vector_type(4)))  float  f32x4;
typedef __attribute__((ext_vector_type(16))) float  f32x16;
typedef __attribute__((ext_vector_type(4)))  float  float4v;

__device__ __forceinline__ void gl_lds16(const void* g, void* l) {
  __builtin_amdgcn_global_load_lds(
      (const __attribute__((address_space(1))) void*)g,
      (__attribute__((address_space(3))) void*)l, 16, 0, 0);
}

__device__ __forceinline__ unsigned pack2(float a, float b) {
  union { bf16x2 v; unsigned u; } x;
  x.v[0] = (__bf16)a; x.v[1] = (__bf16)b;
  return x.u;
}

// ---------------- fp32 -> bf16 elementwise convert (vector4) ---------------
__global__ __launch_bounds__(256) void cvt_bf16(const float* __restrict__ in,
                                                __bf16* __restrict__ out, int n4) {
  int stride = gridDim.x * 256;
  for (int i = blockIdx.x * 256 + threadIdx.x; i < n4; i += stride) {
    float4v v = ((const float4v*)in)[i];
    bf16x4 o;
    o[0] = (__bf16)v[0]; o[1] = (__bf16)v[1];
    o[2] = (__bf16)v[2]; o[3] = (__bf16)v[3];
    ((bf16x4*)out)[i] = o;
  }
}

// ------------- fp32 [K][N] -> bf16 [N][K] tiled transpose+convert ----------
__global__ __launch_bounds__(256) void wtrans(const float* __restrict__ src,
                                              __bf16* __restrict__ dst,
                                              int K, int N) {
  __shared__ float t[64][37];
  const int n0 = blockIdx.x * 32, k0 = blockIdx.y * 64;
  const int tid = threadIdx.x;
  const int kr = tid >> 3, nc = (tid & 7) * 4;
#pragma unroll
  for (int i = 0; i < 2; ++i) {
    float4v v = *(const float4v*)(src + (size_t)(k0 + kr + i * 32) * N + n0 + nc);
    t[kr + i * 32][nc + 0] = v[0];
    t[kr + i * 32][nc + 1] = v[1];
    t[kr + i * 32][nc + 2] = v[2];
    t[kr + i * 32][nc + 3] = v[3];
  }
  __syncthreads();
  const int nr = tid >> 3, kc = (tid & 7) * 8;
  bf16x8 o;
#pragma unroll
  for (int j = 0; j < 8; ++j) o[j] = (__bf16)t[kc + j][nr];
  *(bf16x8*)(dst + (size_t)(n0 + nr) * K + k0 + kc) = o;
}

// --------- gemm1: C[M][N] = A * BT, 256xBN tile (round-15, ~904 TF) --------
template <typename CT, int BN>
__global__ __launch_bounds__(512, 2) void gemm_bt(const __bf16* __restrict__ A,
                                                  const __bf16* __restrict__ BT,
                                                  CT* __restrict__ C,
                                                  int M, int N, int K) {
  constexpr int NB = BN / 64;
  constexpr int NF = BN / 64;
  __shared__ __align__(16) __bf16 As[2][256 * 64];
  __shared__ __align__(16) __bf16 Bs[2][BN * 64];
  const int tid = threadIdx.x;
  const int w = tid >> 6, l = tid & 63;
  const int lr = l & 15, lg = l >> 4;
  const int wm = w >> 2, wn = w & 3;
  const int nwg = gridDim.x * gridDim.y;
  int bid = blockIdx.y * gridDim.x + blockIdx.x;
  bid = (bid & 7) * (nwg >> 3) + (bid >> 3);   // bijective: nwg % 8 == 0
  const int m0 = (bid / gridDim.x) * 256, n0 = (bid % gridDim.x) * BN;
  const int nkt = K >> 6;

  auto stage_all = [&](int T) {
    const int buf = T & 1, k0 = T << 6;
#pragma unroll
    for (int j = 0; j < 4; ++j) {
      int idx = j * 512 + tid;
      int row = idx >> 3;
      int c = (idx & 7) ^ (row & 7);           // pre-swizzled source chunk
      gl_lds16(A + (size_t)(m0 + row) * K + k0 + c * 8,
               As[buf] + (size_t)(j * 512 + w * 64) * 8);
    }
#pragma unroll
    for (int j = 0; j < NB; ++j) {
      int idx = j * 512 + tid;
      int row = idx >> 3;
      int c = (idx & 7) ^ (row & 7);
      gl_lds16(BT + (size_t)(n0 + row) * K + k0 + c * 8,
               Bs[buf] + (size_t)(j * 512 + w * 64) * 8);
    }
  };
  auto rdA = [&](const __bf16* Ab, int mh, int kk, bf16x8* afr) {
#pragma unroll
    for (int m = 0; m < 4; ++m) {
      int row = wm * 128 + (mh * 4 + m) * 16 + lr;
      afr[m] = *(const bf16x8*)(Ab + (size_t)row * 64
                                + (((kk * 4 + lg) ^ (lr & 7)) * 8));
    }
  };
  auto rdB = [&](const __bf16* Bb, int kk, bf16x8* bfr) {
#pragma unroll
    for (int n = 0; n < NF; ++n) {
      int row = wn * (BN / 4) + n * 16 + lr;
      bfr[n] = *(const bf16x8*)(Bb + (size_t)row * 64
                                + (((kk * 4 + lg) ^ (lr & 7)) * 8));
    }
  };
#define SBAR  __builtin_amdgcn_s_barrier()
#define MFMA_CLUSTER(ACC_OFF)                                                   \
  __builtin_amdgcn_s_setprio(1);                                               \
  _Pragma("unroll")                                                             \
  for (int m = 0; m < 4; ++m)                                                   \
    _Pragma("unroll")                                                           \
    for (int n = 0; n < NF; ++n)                                                \
      acc[(ACC_OFF) + m][n] = __builtin_amdgcn_mfma_f32_16x16x32_bf16(          \
          afr[m], bfr[n], acc[(ACC_OFF) + m][n], 0, 0, 0);                      \
  __builtin_amdgcn_s_setprio(0)

  f32x4 acc[8][NF] = {};
  stage_all(0);
  asm volatile("s_waitcnt vmcnt(0)" ::: "memory");
  SBAR;

  for (int T = 0; T < nkt; ++T) {
    const __bf16* Ab = As[T & 1];
    const __bf16* Bb = Bs[T & 1];
    bf16x8 afr[4], bfr[NF];
    rdA(Ab, 0, 0, afr);
    rdB(Bb, 0, bfr);
    if (T + 1 < nkt) stage_all(T + 1);
    MFMA_CLUSTER(0);
    SBAR;
    rdA(Ab, 1, 0, afr);
    MFMA_CLUSTER(4);
    SBAR;
    rdA(Ab, 0, 1, afr);
    rdB(Bb, 1, bfr);
    MFMA_CLUSTER(0);
    SBAR;
    rdA(Ab, 1, 1, afr);
    MFMA_CLUSTER(4);
    asm volatile("s_waitcnt lgkmcnt(0)" ::: "memory");
    if (T + 1 < nkt) asm volatile("s_waitcnt vmcnt(0)" ::: "memory");
    SBAR;
  }
#undef SBAR
#undef MFMA_CLUSTER
  // C/D layout (m89-verified): col = lane&15, row = (lane>>4)*4 + j
#pragma unroll
  for (int m = 0; m < 8; ++m)
#pragma unroll
    for (int n = 0; n < NF; ++n)
#pragma unroll
      for (int j = 0; j < 4; ++j) {
        int row = m0 + wm * 128 + m * 16 + lg * 4 + j;
        int col = n0 + wn * (BN / 4) + n * 16 + lr;
        C[(size_t)row * N + col] = (CT)acc[m][n][j];
      }
}

// --------- gemm2: C = A * BT, 128x192 tile, 8 waves, 2 blocks/CU -----------
template <typename CT>
__global__ __launch_bounds__(512, 2) void gemm2_bt(const __bf16* __restrict__ A,
                                                   const __bf16* __restrict__ BT,
                                                   CT* __restrict__ C,
                                                   int M, int N, int K) {
  __shared__ __align__(16) __bf16 As[2][128 * 64];
  __shared__ __align__(16) __bf16 Bs[2][192 * 64];
  const int tid = threadIdx.x;
  const int w = tid >> 6, l = tid & 63;
  const int lr = l & 15, lg = l >> 4;
  const int wm = w >> 2, wn = w & 3;
  const int nwg = gridDim.x * gridDim.y;
  int bid = blockIdx.y * gridDim.x + blockIdx.x;
  bid = (bid & 7) * (nwg >> 3) + (bid >> 3);   // bijective: nwg % 8 == 0
  const int m0 = (bid / gridDim.x) * 128, n0 = (bid % gridDim.x) * 192;
  const int nkt = K >> 6;

  auto stage_all = [&](int T) {
    const int buf = T & 1, k0 = T << 6;
#pragma unroll
    for (int j = 0; j < 2; ++j) {
      int idx = j * 512 + tid;
      int row = idx >> 3;
      int c = (idx & 7) ^ (row & 7);
      gl_lds16(A + (size_t)(m0 + row) * K + k0 + c * 8,
               As[buf] + (size_t)(j * 512 + w * 64) * 8);
    }
#pragma unroll
    for (int j = 0; j < 3; ++j) {
      int idx = j * 512 + tid;
      int row = idx >> 3;
      int c = (idx & 7) ^ (row & 7);
      gl_lds16(BT + (size_t)(n0 + row) * K + k0 + c * 8,
               Bs[buf] + (size_t)(j * 512 + w * 64) * 8);
    }
  };
  auto rdA = [&](const __bf16* Ab, int kk, bf16x8* afr) {
#pragma unroll
    for (int m = 0; m < 4; ++m) {
      int row = wm * 64 + m * 16 + lr;
      afr[m] = *(const bf16x8*)(Ab + (size_t)row * 64
                                + (((kk * 4 + lg) ^ (lr & 7)) * 8));
    }
  };
  auto rdB = [&](const __bf16* Bb, int kk, bf16x8* bfr) {
#pragma unroll
    for (int n = 0; n < 3; ++n) {
      int row = wn * 48 + n * 16 + lr;
      bfr[n] = *(const bf16x8*)(Bb + (size_t)row * 64
                                + (((kk * 4 + lg) ^ (lr & 7)) * 8));
    }
  };

  f32x4 acc[4][3] = {};
  stage_all(0);
  asm volatile("s_waitcnt vmcnt(0)" ::: "memory");
  __builtin_amdgcn_s_barrier();

  for (int T = 0; T < nkt; ++T) {
    const __bf16* Ab = As[T & 1];
    const __bf16* Bb = Bs[T & 1];
    bf16x8 afr[4], bfr[3];
    rdA(Ab, 0, afr);
    rdB(Bb, 0, bfr);
    if (T + 1 < nkt) stage_all(T + 1);
    __builtin_amdgcn_s_setprio(1);
#pragma unroll
    for (int m = 0; m < 4; ++m)
#pragma unroll
      for (int n = 0; n < 3; ++n)
        acc[m][n] = __builtin_amdgcn_mfma_f32_16x16x32_bf16(afr[m], bfr[n], acc[m][n], 0, 0, 0);
    __builtin_amdgcn_s_setprio(0);
    __builtin_amdgcn_s_barrier();
    rdA(Ab, 1, afr);
    rdB(Bb, 1, bfr);
    __builtin_amdgcn_s_setprio(1);
#pragma unroll
    for (int m = 0; m < 4; ++m)
#pragma unroll
      for (int n = 0; n < 3; ++n)
        acc[m][n] = __builtin_amdgcn_mfma_f32_16x16x32_bf16(afr[m], bfr[n], acc[m][n], 0, 0, 0);
    __builtin_amdgcn_s_setprio(0);
    asm volatile("s_waitcnt lgkmcnt(0)" ::: "memory");
    if (T + 1 < nkt) asm volatile("s_waitcnt vmcnt(0)" ::: "memory");
    __builtin_amdgcn_s_barrier();
  }
#pragma unroll
  for (int m = 0; m < 4; ++m)
#pragma unroll
    for (int n = 0; n < 3; ++n)
#pragma unroll
      for (int j = 0; j < 4; ++j) {
        int row = m0 + wm * 64 + m * 16 + lg * 4 + j;
        int col = n0 + wn * 48 + n * 16 + lr;
        C[(size_t)row * N + col] = (CT)acc[m][n][j];
      }
}

// ------ RoPE on Q (scaled by log2(e)/sqrt(HD)) and K, bf16 -> bf16 ---------
__global__ __launch_bounds__(256) void rope_qk(const __bf16* __restrict__ qkv,
                                               const float* __restrict__ cosT,
                                               const float* __restrict__ sinT,
                                               __bf16* __restrict__ Qo,
                                               __bf16* __restrict__ Ko) {
  const int s = blockIdx.x;
  const __bf16* base = qkv + (size_t)s * NQK;
  const float* ct = cosT + s * HD_;
  const float* st = sinT + s * HD_;
  const float scale = 0.1275174313f;  // (1/sqrt(128)) * log2(e)
  for (int q4 = threadIdx.x; q4 < H_ * HD_ / 4; q4 += 256) {
    int h = q4 >> 5, d = (q4 & 31) * 4;
    bf16x4 x  = *(const bf16x4*)(base + h * HD_ + d);
    bf16x4 xr = (d < 64) ? *(const bf16x4*)(base + h * HD_ + d + 64)
                         : *(const bf16x4*)(base + h * HD_ + d - 64);
    float4v c4 = *(const float4v*)(ct + d);
    float4v s4 = *(const float4v*)(st + d);
    bf16x4 o;
#pragma unroll
    for (int j = 0; j < 4; ++j) {
      float r = (d < 64) ? -(float)xr[j] : (float)xr[j];
      o[j] = (__bf16)(((float)x[j] * c4[j] + r * s4[j]) * scale);
    }
    *(bf16x4*)(Qo + ((size_t)s * H_ + h) * HD_ + d) = o;
  }
  for (int q4 = threadIdx.x; q4 < KV_ * HD_ / 4; q4 += 256) {
    int h = q4 >> 5, d = (q4 & 31) * 4;
    const __bf16* kb = base + H_ * HD_;
    bf16x4 x  = *(const bf16x4*)(kb + h * HD_ + d);
    bf16x4 xr = (d < 64) ? *(const bf16x4*)(kb + h * HD_ + d + 64)
                         : *(const bf16x4*)(kb + h * HD_ + d - 64);
    float4v c4 = *(const float4v*)(ct + d);
    float4v s4 = *(const float4v*)(st + d);
    bf16x4 o;
#pragma unroll
    for (int j = 0; j < 4; ++j) {
      float r = (d < 64) ? -(float)xr[j] : (float)xr[j];
      o[j] = (__bf16)((float)x[j] * c4[j] + r * s4[j]);
    }
    *(bf16x4*)(Ko + ((size_t)s * KV_ + h) * HD_ + d) = o;
  }
}

// -------- V transpose: qkv[s][7168 + h*128 + d] bf16 -> Vt[h][d][s] --------
__global__ __launch_bounds__(256) void v_trans(const __bf16* __restrict__ qkv,
                                               __bf16* __restrict__ Vt) {
  __shared__ __bf16 t[32][36];
  const int s0 = blockIdx.x * 32, d0 = blockIdx.y * 32, h = blockIdx.z;
  const int tx = threadIdx.x, ty = threadIdx.y;  // (8, 32)
  *(bf16x4*)&t[ty][tx * 4] =
      *(const bf16x4*)(qkv + (size_t)(s0 + ty) * NQK + (H_ + KV_) * HD_ + h * HD_ + d0 + tx * 4);
  __syncthreads();
  bf16x4 o;
#pragma unroll
  for (int j = 0; j < 4; ++j) o[j] = t[tx * 4 + j][ty];
  *(bf16x4*)(Vt + ((size_t)h * HD_ + d0 + ty) * S_ + s0 + tx * 4) = o;
}

// -------------------- causal GQA flash attention ---------------------------
// Grid (S/128, H), block 256 = 4 waves; wave w owns q-rows qb+w*32..+31.
// bx REVERSED (heaviest blocks first).  K tile [64][128] LDS-staged
// (XOR-swizzled, dbuf).  V^T read DIRECT global->register (L2-hot; m169:
// staging L2-fit data is pure overhead); vf issued right after QK^T so
// softmax VALU work covers the latency.  Swapped QK^T; softmax in-lane +
// shfl_xor(32); PV: O^T = mfma(A=vf, B=P-frag via packed shfl exchange).
__global__ __launch_bounds__(256, 2) void attn(const __bf16* __restrict__ Q,
                                               const __bf16* __restrict__ Kb,
                                               const __bf16* __restrict__ Vt,
                                               __bf16* __restrict__ O) {
  __shared__ __align__(16) __bf16 Ks[2][64 * 128];
  const int bx = gridDim.x - 1 - blockIdx.x;   // longest-first dispatch
  const int h = blockIdx.y, kvh = h / REP;
  const int tid = threadIdx.x, w = tid >> 6, l = tid & 63;
  const int c = l & 31, g = l >> 5;
  const int qb = bx * 128;
  const int qrow = qb + w * 32 + c;
  const int tmax_w = (qb + w * 32 + 31) >> 6;
  const int NT = (qb >> 6) + 2;

  auto stage = [&](int t) {                    // K only: 4 gl_lds/thread
    const int buf = t & 1;
    const int kbase = t << 6;
#pragma unroll
    for (int j = 0; j < 4; ++j) {
      int idx = j * 256 + tid;
      int row = idx >> 4, cc = (idx & 15) ^ (row & 15);
      gl_lds16(Kb + ((size_t)(kbase + row) * KV_ + kvh) * HD_ + cc * 8,
               Ks[buf] + (size_t)(j * 256 + w * 64) * 8);
    }
  };

  bf16x8 qf[8];
  const __bf16* qp = Q + ((size_t)qrow * H_ + h) * HD_ + g * 8;
#pragma unroll
  for (int st = 0; st < 8; ++st) qf[st] = *(const bf16x8*)(qp + st * 16);

  f32x16 o[4] = {};
  float m = -1e30f, lsum = 0.f;

  stage(0);
  __syncthreads();
  for (int t = 0; t < NT; ++t) {
    const int buf = t & 1;
    if (t + 1 < NT) stage(t + 1);
    if (t <= tmax_w) {
      const int kbase = t << 6;
      f32x16 s0 = {}, s1 = {};
      __builtin_amdgcn_s_setprio(1);
#pragma unroll
      for (int st = 0; st < 8; ++st) {
        int ch = ((st * 2 + g) ^ (c & 15)) * 8;
        bf16x8 k0 = *(const bf16x8*)(Ks[buf] + (size_t)c * 128 + ch);
        bf16x8 k1 = *(const bf16x8*)(Ks[buf] + (size_t)(32 + c) * 128 + ch);
        s0 = __builtin_amdgcn_mfma_f32_32x32x16_bf16(k0, qf[st], s0, 0, 0, 0);
        s1 = __builtin_amdgcn_mfma_f32_32x32x16_bf16(k1, qf[st], s1, 0, 0, 0);
      }
      __builtin_amdgcn_s_setprio(0);
      // V^T fragments direct from global (L2-hot); latency hides under softmax
      bf16x8 vf[4][4];
#pragma unroll
      for (int db = 0; db < 4; ++db)
#pragma unroll
        for (int s = 0; s < 4; ++s)
          vf[db][s] = *(const bf16x8*)(Vt + ((size_t)(kvh * HD_ + db * 32 + c)) * S_
                                       + kbase + s * 16 + g * 8);
      if (t == tmax_w) {
#pragma unroll
        for (int r = 0; r < 16; ++r) {
          int krow = (r & 3) + 8 * (r >> 2) + 4 * g;
          if (kbase + krow > qrow)      s0[r] = -1e30f;
          if (kbase + 32 + krow > qrow) s1[r] = -1e30f;
        }
      }
      float mj = s0[0];
#pragma unroll
      for (int r = 1; r < 16; ++r) mj = fmaxf(mj, s0[r]);
#pragma unroll
      for (int r = 0; r < 16; ++r) mj = fmaxf(mj, s1[r]);
      mj = fmaxf(mj, __shfl_xor(mj, 32));
      float mnew = fmaxf(m, mj);
      float sc = __builtin_amdgcn_exp2f(m - mnew);
      float rs = 0.f;
      float p0[16], p1[16];
#pragma unroll
      for (int r = 0; r < 16; ++r) { p0[r] = __builtin_amdgcn_exp2f(s0[r] - mnew); rs += p0[r]; }
#pragma unroll
      for (int r = 0; r < 16; ++r) { p1[r] = __builtin_amdgcn_exp2f(s1[r] - mnew); rs += p1[r]; }
      rs += __shfl_xor(rs, 32);
      lsum = lsum * sc + rs;
      m = mnew;
#pragma unroll
      for (int db = 0; db < 4; ++db)
#pragma unroll
        for (int r = 0; r < 16; ++r) o[db][r] *= sc;
      unsigned bq[4][4];
#pragma unroll
      for (int n = 0; n < 2; ++n)
#pragma unroll
        for (int tq = 0; tq < 2; ++tq) {
          const float* pp = n ? p1 : p0;
          unsigned q0 = pack2(pp[8 * tq + 0], pp[8 * tq + 1]);
          unsigned q1 = pack2(pp[8 * tq + 2], pp[8 * tq + 3]);
          unsigned q2 = pack2(pp[8 * tq + 4], pp[8 * tq + 5]);
          unsigned q3 = pack2(pp[8 * tq + 6], pp[8 * tq + 7]);
          unsigned v0 = g ? q0 : q2;
          unsigned v1 = g ? q1 : q3;
          unsigned sh0 = (unsigned)__shfl_xor((int)v0, 32);
          unsigned sh1 = (unsigned)__shfl_xor((int)v1, 32);
          int s = n * 2 + tq;
          bq[s][0] = g ? sh0 : q0;
          bq[s][1] = g ? sh1 : q1;
          bq[s][2] = g ? q2 : sh0;
          bq[s][3] = g ? q3 : sh1;
        }
      __builtin_amdgcn_s_setprio(1);
#pragma unroll
      for (int s = 0; s < 4; ++s) {
        union { unsigned u[4]; bf16x8 v; } bb;
        bb.u[0] = bq[s][0]; bb.u[1] = bq[s][1]; bb.u[2] = bq[s][2]; bb.u[3] = bq[s][3];
#pragma unroll
        for (int db = 0; db < 4; ++db)
          o[db] = __builtin_amdgcn_mfma_f32_32x32x16_bf16(vf[db][s], bb.v, o[db], 0, 0, 0);
      }
      __builtin_amdgcn_s_setprio(0);
    }
    if (t + 1 < NT) __syncthreads();
  }
  float inv = 1.f / lsum;
#pragma unroll
  for (int db = 0; db < 4; ++db)
#pragma unroll
    for (int rg = 0; rg < 4; ++rg) {
      bf16x4 ov;
#pragma unroll
      for (int j = 0; j < 4; ++j) ov[j] = (__bf16)(o[db][rg * 4 + j] * inv);
      *(bf16x4*)(O + (size_t)qrow * D_ + h * HD_ + db * 32 + rg * 8 + g * 4) = ov;
    }
}

// ---------------------------------------------------------------------------
extern "C" void kernel_launch(void* const* d_in, const int* in_sizes, int n_in,
                              void* d_out, int out_size, void* d_ws, size_t ws_size,
                              hipStream_t stream) {
  const float* hidden = (const float*)d_in[0];
  const float* cosT   = (const float*)d_in[1];
  const float* sinT   = (const float*)d_in[2];
  const float* w_qkv  = (const float*)d_in[3];
  const float* w_out  = (const float*)d_in[4];
  float* out = (float*)d_out;
  char* ws = (char*)d_ws;

  __bf16* wT   = (__bf16*)ws;
  __bf16* hb   = (__bf16*)(ws + 100663296);
  __bf16* qkvb = (__bf16*)(ws + 100663296 + 25165824);
  __bf16* q_b  = (__bf16*)(ws + 100663296 + 25165824 + 33554432);
  __bf16* k_b  = q_b + (size_t)S_ * H_ * HD_;
  __bf16* vt_b = k_b + (size_t)S_ * KV_ * HD_;

  cvt_bf16<<<dim3(2048), dim3(256), 0, stream>>>(hidden, hb, (int)((size_t)S_ * D_ / 4));
  wtrans<<<dim3(NQK / 32, D_ / 64), dim3(256), 0, stream>>>(w_qkv, wT, D_, NQK);
  gemm_bt<__bf16, 256><<<dim3(NQK / 256, S_ / 256), dim3(512), 0, stream>>>(hb, wT, qkvb, S_, NQK, D_);
  rope_qk<<<dim3(S_), dim3(256), 0, stream>>>(qkvb, cosT, sinT, q_b, k_b);
  v_trans<<<dim3(S_ / 32, HD_ / 32, KV_), dim3(8, 32), 0, stream>>>(qkvb, vt_b);
  wtrans<<<dim3(D_ / 32, D_ / 64), dim3(256), 0, stream>>>(w_out, wT, D_, D_);
  attn<<<dim3(S_ / 128, H_), dim3(256), 0, stream>>>(q_b, k_b, vt_b, hb);
  gemm2_bt<float><<<dim3(D_ / 192, S_ / 128), dim3(512), 0, stream>>>(hb, wT, out, S_, D_, D_);
}

// Round 19
// 619.581 us; speedup vs baseline: 1.1051x; 1.1051x over previous
//
#include <hip/hip_runtime.h>

// ---------------------------------------------------------------------------
// DbrxAttention on MI355X (gfx950).
// gemm1: 256x256, BK=64, dbuf LDS, relaxed 4-phase schedule, XOR-8 swizzle,
//   setprio (~904 TF; 8-phase transplants tested rounds 5/6/9/16 - all <=).
// gemm2: 128x192, 80 KB LDS -> 2 blocks/CU (round-15 winner).
// Attention: 4-wave blocks, K/V LDS-staged (swizzled, dbuf), swapped-QK^T
//   32x32x16, softmax in registers (exp2 domain), reversed bx, defer-max
//   THR=8 (T13).  [V-direct tested round 18: 2.5x regression - reverted.]
// wtrans: 64kx32n tile, float4 reads + bf16x8 writes.
// ---------------------------------------------------------------------------

#define S_   2048
#define D_   6144
#define H_   48
#define KV_  8
#define HD_  128
#define NQK  8192
#define REP  6

typedef __attribute__((ext_vector_type(8)))  __bf16 bf16x8;
typedef __attribute__((ext_vector_type(4)))  __bf16 bf16x4;
typedef __attribute__((ext_vector_type(2)))  __bf16 bf16x2;
typedef __attribute__((ext_vector_type(4)))  float  f32x4;
typedef __attribute__((ext_vector_type(16))) float  f32x16;
typedef __attribute__((ext_vector_type(4)))  float  float4v;

__device__ __forceinline__ void gl_lds16(const void* g, void* l) {
  __builtin_amdgcn_global_load_lds(
      (const __attribute__((address_space(1))) void*)g,
      (__attribute__((address_space(3))) void*)l, 16, 0, 0);
}

__device__ __forceinline__ unsigned pack2(float a, float b) {
  union { bf16x2 v; unsigned u; } x;
  x.v[0] = (__bf16)a; x.v[1] = (__bf16)b;
  return x.u;
}

// ---------------- fp32 -> bf16 elementwise convert (vector4) ---------------
__global__ __launch_bounds__(256) void cvt_bf16(const float* __restrict__ in,
                                                __bf16* __restrict__ out, int n4) {
  int stride = gridDim.x * 256;
  for (int i = blockIdx.x * 256 + threadIdx.x; i < n4; i += stride) {
    float4v v = ((const float4v*)in)[i];
    bf16x4 o;
    o[0] = (__bf16)v[0]; o[1] = (__bf16)v[1];
    o[2] = (__bf16)v[2]; o[3] = (__bf16)v[3];
    ((bf16x4*)out)[i] = o;
  }
}

// ------------- fp32 [K][N] -> bf16 [N][K] tiled transpose+convert ----------
__global__ __launch_bounds__(256) void wtrans(const float* __restrict__ src,
                                              __bf16* __restrict__ dst,
                                              int K, int N) {
  __shared__ float t[64][37];
  const int n0 = blockIdx.x * 32, k0 = blockIdx.y * 64;
  const int tid = threadIdx.x;
  const int kr = tid >> 3, nc = (tid & 7) * 4;
#pragma unroll
  for (int i = 0; i < 2; ++i) {
    float4v v = *(const float4v*)(src + (size_t)(k0 + kr + i * 32) * N + n0 + nc);
    t[kr + i * 32][nc + 0] = v[0];
    t[kr + i * 32][nc + 1] = v[1];
    t[kr + i * 32][nc + 2] = v[2];
    t[kr + i * 32][nc + 3] = v[3];
  }
  __syncthreads();
  const int nr = tid >> 3, kc = (tid & 7) * 8;
  bf16x8 o;
#pragma unroll
  for (int j = 0; j < 8; ++j) o[j] = (__bf16)t[kc + j][nr];
  *(bf16x8*)(dst + (size_t)(n0 + nr) * K + k0 + kc) = o;
}

// --------- gemm1: C[M][N] = A * BT, 256xBN tile (round-15, ~904 TF) --------
template <typename CT, int BN>
__global__ __launch_bounds__(512, 2) void gemm_bt(const __bf16* __restrict__ A,
                                                  const __bf16* __restrict__ BT,
                                                  CT* __restrict__ C,
                                                  int M, int N, int K) {
  constexpr int NB = BN / 64;
  constexpr int NF = BN / 64;
  __shared__ __align__(16) __bf16 As[2][256 * 64];
  __shared__ __align__(16) __bf16 Bs[2][BN * 64];
  const int tid = threadIdx.x;
  const int w = tid >> 6, l = tid & 63;
  const int lr = l & 15, lg = l >> 4;
  const int wm = w >> 2, wn = w & 3;
  const int nwg = gridDim.x * gridDim.y;
  int bid = blockIdx.y * gridDim.x + blockIdx.x;
  bid = (bid & 7) * (nwg >> 3) + (bid >> 3);   // bijective: nwg % 8 == 0
  const int m0 = (bid / gridDim.x) * 256, n0 = (bid % gridDim.x) * BN;
  const int nkt = K >> 6;

  auto stage_all = [&](int T) {
    const int buf = T & 1, k0 = T << 6;
#pragma unroll
    for (int j = 0; j < 4; ++j) {
      int idx = j * 512 + tid;
      int row = idx >> 3;
      int c = (idx & 7) ^ (row & 7);           // pre-swizzled source chunk
      gl_lds16(A + (size_t)(m0 + row) * K + k0 + c * 8,
               As[buf] + (size_t)(j * 512 + w * 64) * 8);
    }
#pragma unroll
    for (int j = 0; j < NB; ++j) {
      int idx = j * 512 + tid;
      int row = idx >> 3;
      int c = (idx & 7) ^ (row & 7);
      gl_lds16(BT + (size_t)(n0 + row) * K + k0 + c * 8,
               Bs[buf] + (size_t)(j * 512 + w * 64) * 8);
    }
  };
  auto rdA = [&](const __bf16* Ab, int mh, int kk, bf16x8* afr) {
#pragma unroll
    for (int m = 0; m < 4; ++m) {
      int row = wm * 128 + (mh * 4 + m) * 16 + lr;
      afr[m] = *(const bf16x8*)(Ab + (size_t)row * 64
                                + (((kk * 4 + lg) ^ (lr & 7)) * 8));
    }
  };
  auto rdB = [&](const __bf16* Bb, int kk, bf16x8* bfr) {
#pragma unroll
    for (int n = 0; n < NF; ++n) {
      int row = wn * (BN / 4) + n * 16 + lr;
      bfr[n] = *(const bf16x8*)(Bb + (size_t)row * 64
                                + (((kk * 4 + lg) ^ (lr & 7)) * 8));
    }
  };
#define SBAR  __builtin_amdgcn_s_barrier()
#define MFMA_CLUSTER(ACC_OFF)                                                   \
  __builtin_amdgcn_s_setprio(1);                                               \
  _Pragma("unroll")                                                             \
  for (int m = 0; m < 4; ++m)                                                   \
    _Pragma("unroll")                                                           \
    for (int n = 0; n < NF; ++n)                                                \
      acc[(ACC_OFF) + m][n] = __builtin_amdgcn_mfma_f32_16x16x32_bf16(          \
          afr[m], bfr[n], acc[(ACC_OFF) + m][n], 0, 0, 0);                      \
  __builtin_amdgcn_s_setprio(0)

  f32x4 acc[8][NF] = {};
  stage_all(0);
  asm volatile("s_waitcnt vmcnt(0)" ::: "memory");
  SBAR;

  for (int T = 0; T < nkt; ++T) {
    const __bf16* Ab = As[T & 1];
    const __bf16* Bb = Bs[T & 1];
    bf16x8 afr[4], bfr[NF];
    rdA(Ab, 0, 0, afr);
    rdB(Bb, 0, bfr);
    if (T + 1 < nkt) stage_all(T + 1);
    MFMA_CLUSTER(0);
    SBAR;
    rdA(Ab, 1, 0, afr);
    MFMA_CLUSTER(4);
    SBAR;
    rdA(Ab, 0, 1, afr);
    rdB(Bb, 1, bfr);
    MFMA_CLUSTER(0);
    SBAR;
    rdA(Ab, 1, 1, afr);
    MFMA_CLUSTER(4);
    asm volatile("s_waitcnt lgkmcnt(0)" ::: "memory");
    if (T + 1 < nkt) asm volatile("s_waitcnt vmcnt(0)" ::: "memory");
    SBAR;
  }
#undef SBAR
#undef MFMA_CLUSTER
  // C/D layout (m89-verified): col = lane&15, row = (lane>>4)*4 + j
#pragma unroll
  for (int m = 0; m < 8; ++m)
#pragma unroll
    for (int n = 0; n < NF; ++n)
#pragma unroll
      for (int j = 0; j < 4; ++j) {
        int row = m0 + wm * 128 + m * 16 + lg * 4 + j;
        int col = n0 + wn * (BN / 4) + n * 16 + lr;
        C[(size_t)row * N + col] = (CT)acc[m][n][j];
      }
}

// --------- gemm2: C = A * BT, 128x192 tile, 8 waves, 2 blocks/CU -----------
template <typename CT>
__global__ __launch_bounds__(512, 2) void gemm2_bt(const __bf16* __restrict__ A,
                                                   const __bf16* __restrict__ BT,
                                                   CT* __restrict__ C,
                                                   int M, int N, int K) {
  __shared__ __align__(16) __bf16 As[2][128 * 64];
  __shared__ __align__(16) __bf16 Bs[2][192 * 64];
  const int tid = threadIdx.x;
  const int w = tid >> 6, l = tid & 63;
  const int lr = l & 15, lg = l >> 4;
  const int wm = w >> 2, wn = w & 3;
  const int nwg = gridDim.x * gridDim.y;
  int bid = blockIdx.y * gridDim.x + blockIdx.x;
  bid = (bid & 7) * (nwg >> 3) + (bid >> 3);   // bijective: nwg % 8 == 0
  const int m0 = (bid / gridDim.x) * 128, n0 = (bid % gridDim.x) * 192;
  const int nkt = K >> 6;

  auto stage_all = [&](int T) {
    const int buf = T & 1, k0 = T << 6;
#pragma unroll
    for (int j = 0; j < 2; ++j) {
      int idx = j * 512 + tid;
      int row = idx >> 3;
      int c = (idx & 7) ^ (row & 7);
      gl_lds16(A + (size_t)(m0 + row) * K + k0 + c * 8,
               As[buf] + (size_t)(j * 512 + w * 64) * 8);
    }
#pragma unroll
    for (int j = 0; j < 3; ++j) {
      int idx = j * 512 + tid;
      int row = idx >> 3;
      int c = (idx & 7) ^ (row & 7);
      gl_lds16(BT + (size_t)(n0 + row) * K + k0 + c * 8,
               Bs[buf] + (size_t)(j * 512 + w * 64) * 8);
    }
  };
  auto rdA = [&](const __bf16* Ab, int kk, bf16x8* afr) {
#pragma unroll
    for (int m = 0; m < 4; ++m) {
      int row = wm * 64 + m * 16 + lr;
      afr[m] = *(const bf16x8*)(Ab + (size_t)row * 64
                                + (((kk * 4 + lg) ^ (lr & 7)) * 8));
    }
  };
  auto rdB = [&](const __bf16* Bb, int kk, bf16x8* bfr) {
#pragma unroll
    for (int n = 0; n < 3; ++n) {
      int row = wn * 48 + n * 16 + lr;
      bfr[n] = *(const bf16x8*)(Bb + (size_t)row * 64
                                + (((kk * 4 + lg) ^ (lr & 7)) * 8));
    }
  };

  f32x4 acc[4][3] = {};
  stage_all(0);
  asm volatile("s_waitcnt vmcnt(0)" ::: "memory");
  __builtin_amdgcn_s_barrier();

  for (int T = 0; T < nkt; ++T) {
    const __bf16* Ab = As[T & 1];
    const __bf16* Bb = Bs[T & 1];
    bf16x8 afr[4], bfr[3];
    rdA(Ab, 0, afr);
    rdB(Bb, 0, bfr);
    if (T + 1 < nkt) stage_all(T + 1);
    __builtin_amdgcn_s_setprio(1);
#pragma unroll
    for (int m = 0; m < 4; ++m)
#pragma unroll
      for (int n = 0; n < 3; ++n)
        acc[m][n] = __builtin_amdgcn_mfma_f32_16x16x32_bf16(afr[m], bfr[n], acc[m][n], 0, 0, 0);
    __builtin_amdgcn_s_setprio(0);
    __builtin_amdgcn_s_barrier();
    rdA(Ab, 1, afr);
    rdB(Bb, 1, bfr);
    __builtin_amdgcn_s_setprio(1);
#pragma unroll
    for (int m = 0; m < 4; ++m)
#pragma unroll
      for (int n = 0; n < 3; ++n)
        acc[m][n] = __builtin_amdgcn_mfma_f32_16x16x32_bf16(afr[m], bfr[n], acc[m][n], 0, 0, 0);
    __builtin_amdgcn_s_setprio(0);
    asm volatile("s_waitcnt lgkmcnt(0)" ::: "memory");
    if (T + 1 < nkt) asm volatile("s_waitcnt vmcnt(0)" ::: "memory");
    __builtin_amdgcn_s_barrier();
  }
#pragma unroll
  for (int m = 0; m < 4; ++m)
#pragma unroll
    for (int n = 0; n < 3; ++n)
#pragma unroll
      for (int j = 0; j < 4; ++j) {
        int row = m0 + wm * 64 + m * 16 + lg * 4 + j;
        int col = n0 + wn * 48 + n * 16 + lr;
        C[(size_t)row * N + col] = (CT)acc[m][n][j];
      }
}

// ------ RoPE on Q (scaled by log2(e)/sqrt(HD)) and K, bf16 -> bf16 ---------
__global__ __launch_bounds__(256) void rope_qk(const __bf16* __restrict__ qkv,
                                               const float* __restrict__ cosT,
                                               const float* __restrict__ sinT,
                                               __bf16* __restrict__ Qo,
                                               __bf16* __restrict__ Ko) {
  const int s = blockIdx.x;
  const __bf16* base = qkv + (size_t)s * NQK;
  const float* ct = cosT + s * HD_;
  const float* st = sinT + s * HD_;
  const float scale = 0.1275174313f;  // (1/sqrt(128)) * log2(e)
  for (int q4 = threadIdx.x; q4 < H_ * HD_ / 4; q4 += 256) {
    int h = q4 >> 5, d = (q4 & 31) * 4;
    bf16x4 x  = *(const bf16x4*)(base + h * HD_ + d);
    bf16x4 xr = (d < 64) ? *(const bf16x4*)(base + h * HD_ + d + 64)
                         : *(const bf16x4*)(base + h * HD_ + d - 64);
    float4v c4 = *(const float4v*)(ct + d);
    float4v s4 = *(const float4v*)(st + d);
    bf16x4 o;
#pragma unroll
    for (int j = 0; j < 4; ++j) {
      float r = (d < 64) ? -(float)xr[j] : (float)xr[j];
      o[j] = (__bf16)(((float)x[j] * c4[j] + r * s4[j]) * scale);
    }
    *(bf16x4*)(Qo + ((size_t)s * H_ + h) * HD_ + d) = o;
  }
  for (int q4 = threadIdx.x; q4 < KV_ * HD_ / 4; q4 += 256) {
    int h = q4 >> 5, d = (q4 & 31) * 4;
    const __bf16* kb = base + H_ * HD_;
    bf16x4 x  = *(const bf16x4*)(kb + h * HD_ + d);
    bf16x4 xr = (d < 64) ? *(const bf16x4*)(kb + h * HD_ + d + 64)
                         : *(const bf16x4*)(kb + h * HD_ + d - 64);
    float4v c4 = *(const float4v*)(ct + d);
    float4v s4 = *(const float4v*)(st + d);
    bf16x4 o;
#pragma unroll
    for (int j = 0; j < 4; ++j) {
      float r = (d < 64) ? -(float)xr[j] : (float)xr[j];
      o[j] = (__bf16)((float)x[j] * c4[j] + r * s4[j]);
    }
    *(bf16x4*)(Ko + ((size_t)s * KV_ + h) * HD_ + d) = o;
  }
}

// -------- V transpose: qkv[s][7168 + h*128 + d] bf16 -> Vt[h][d][s] --------
__global__ __launch_bounds__(256) void v_trans(const __bf16* __restrict__ qkv,
                                               __bf16* __restrict__ Vt) {
  __shared__ __bf16 t[32][36];
  const int s0 = blockIdx.x * 32, d0 = blockIdx.y * 32, h = blockIdx.z;
  const int tx = threadIdx.x, ty = threadIdx.y;  // (8, 32)
  *(bf16x4*)&t[ty][tx * 4] =
      *(const bf16x4*)(qkv + (size_t)(s0 + ty) * NQK + (H_ + KV_) * HD_ + h * HD_ + d0 + tx * 4);
  __syncthreads();
  bf16x4 o;
#pragma unroll
  for (int j = 0; j < 4; ++j) o[j] = t[tx * 4 + j][ty];
  *(bf16x4*)(Vt + ((size_t)h * HD_ + d0 + ty) * S_ + s0 + tx * 4) = o;
}

// -------------------- causal GQA flash attention ---------------------------
// Grid (S/128, H), block 256 = 4 waves; wave w owns q-rows qb+w*32..+31.
// bx REVERSED (heaviest blocks first).  K tile [64][128] and V^T tile
// [128][64] LDS-staged (XOR-swizzled, dbuf; V-direct tested round 18 =
// 2.5x regression).  Swapped QK^T; softmax in-lane + shfl_xor(32);
// defer-max THR=8 (T13): skip O-rescale when tile max grows < 8 (exp2 dom).
__global__ __launch_bounds__(256, 2) void attn(const __bf16* __restrict__ Q,
                                               const __bf16* __restrict__ Kb,
                                               const __bf16* __restrict__ Vt,
                                               __bf16* __restrict__ O) {
  __shared__ __align__(16) __bf16 Ks[2][64 * 128];
  __shared__ __align__(16) __bf16 Vs[2][128 * 64];
  const int bx = gridDim.x - 1 - blockIdx.x;   // longest-first dispatch
  const int h = blockIdx.y, kvh = h / REP;
  const int tid = threadIdx.x, w = tid >> 6, l = tid & 63;
  const int c = l & 31, g = l >> 5;
  const int qb = bx * 128;
  const int qrow = qb + w * 32 + c;
  const int tmax_w = (qb + w * 32 + 31) >> 6;
  const int NT = (qb >> 6) + 2;

  auto stage = [&](int t) {
    const int buf = t & 1;
    const int kbase = t << 6;
#pragma unroll
    for (int j = 0; j < 4; ++j) {
      int idx = j * 256 + tid;
      int row = idx >> 4, cc = (idx & 15) ^ (row & 15);
      gl_lds16(Kb + ((size_t)(kbase + row) * KV_ + kvh) * HD_ + cc * 8,
               Ks[buf] + (size_t)(j * 256 + w * 64) * 8);
    }
#pragma unroll
    for (int j = 0; j < 4; ++j) {
      int idx = j * 256 + tid;
      int row = idx >> 3, cc = (idx & 7) ^ (row & 7);
      gl_lds16(Vt + (size_t)(kvh * HD_ + row) * S_ + kbase + cc * 8,
               Vs[buf] + (size_t)(j * 256 + w * 64) * 8);
    }
  };

  bf16x8 qf[8];
  const __bf16* qp = Q + ((size_t)qrow * H_ + h) * HD_ + g * 8;
#pragma unroll
  for (int st = 0; st < 8; ++st) qf[st] = *(const bf16x8*)(qp + st * 16);

  f32x16 o[4] = {};
  float m = -1e30f, lsum = 0.f;

  stage(0);
  __syncthreads();
  for (int t = 0; t < NT; ++t) {
    const int buf = t & 1;
    if (t + 1 < NT) stage(t + 1);
    if (t <= tmax_w) {
      const int kbase = t << 6;
      f32x16 s0 = {}, s1 = {};
      __builtin_amdgcn_s_setprio(1);
#pragma unroll
      for (int st = 0; st < 8; ++st) {
        int ch = ((st * 2 + g) ^ (c & 15)) * 8;
        bf16x8 k0 = *(const bf16x8*)(Ks[buf] + (size_t)c * 128 + ch);
        bf16x8 k1 = *(const bf16x8*)(Ks[buf] + (size_t)(32 + c) * 128 + ch);
        s0 = __builtin_amdgcn_mfma_f32_32x32x16_bf16(k0, qf[st], s0, 0, 0, 0);
        s1 = __builtin_amdgcn_mfma_f32_32x32x16_bf16(k1, qf[st], s1, 0, 0, 0);
      }
      __builtin_amdgcn_s_setprio(0);
      if (t == tmax_w) {
#pragma unroll
        for (int r = 0; r < 16; ++r) {
          int krow = (r & 3) + 8 * (r >> 2) + 4 * g;
          if (kbase + krow > qrow)      s0[r] = -1e30f;
          if (kbase + 32 + krow > qrow) s1[r] = -1e30f;
        }
      }
      // online softmax (exp2 domain) with defer-max (T13, THR=8)
      float mj = s0[0];
#pragma unroll
      for (int r = 1; r < 16; ++r) mj = fmaxf(mj, s0[r]);
#pragma unroll
      for (int r = 0; r < 16; ++r) mj = fmaxf(mj, s1[r]);
      mj = fmaxf(mj, __shfl_xor(mj, 32));
      if (!__all(mj - m <= 8.0f)) {            // rescale only on real growth
        float mnew = fmaxf(m, mj);
        float sc = __builtin_amdgcn_exp2f(m - mnew);
        lsum *= sc;
#pragma unroll
        for (int db = 0; db < 4; ++db)
#pragma unroll
          for (int r = 0; r < 16; ++r) o[db][r] *= sc;
        m = mnew;
      }
      float rs = 0.f;
      float p0[16], p1[16];
#pragma unroll
      for (int r = 0; r < 16; ++r) { p0[r] = __builtin_amdgcn_exp2f(s0[r] - m); rs += p0[r]; }
#pragma unroll
      for (int r = 0; r < 16; ++r) { p1[r] = __builtin_amdgcn_exp2f(s1[r] - m); rs += p1[r]; }
      rs += __shfl_xor(rs, 32);
      lsum += rs;
      unsigned bq[4][4];
#pragma unroll
      for (int n = 0; n < 2; ++n)
#pragma unroll
        for (int tq = 0; tq < 2; ++tq) {
          const float* pp = n ? p1 : p0;
          unsigned q0 = pack2(pp[8 * tq + 0], pp[8 * tq + 1]);
          unsigned q1 = pack2(pp[8 * tq + 2], pp[8 * tq + 3]);
          unsigned q2 = pack2(pp[8 * tq + 4], pp[8 * tq + 5]);
          unsigned q3 = pack2(pp[8 * tq + 6], pp[8 * tq + 7]);
          unsigned v0 = g ? q0 : q2;
          unsigned v1 = g ? q1 : q3;
          unsigned sh0 = (unsigned)__shfl_xor((int)v0, 32);
          unsigned sh1 = (unsigned)__shfl_xor((int)v1, 32);
          int s = n * 2 + tq;
          bq[s][0] = g ? sh0 : q0;
          bq[s][1] = g ? sh1 : q1;
          bq[s][2] = g ? q2 : sh0;
          bq[s][3] = g ? q3 : sh1;
        }
      __builtin_amdgcn_s_setprio(1);
#pragma unroll
      for (int s = 0; s < 4; ++s) {
        union { unsigned u[4]; bf16x8 v; } bb;
        bb.u[0] = bq[s][0]; bb.u[1] = bq[s][1]; bb.u[2] = bq[s][2]; bb.u[3] = bq[s][3];
#pragma unroll
        for (int db = 0; db < 4; ++db) {
          int ch = ((s * 2 + g) ^ (c & 7)) * 8;
          bf16x8 vfr = *(const bf16x8*)(Vs[buf] + (size_t)(db * 32 + c) * 64 + ch);
          o[db] = __builtin_amdgcn_mfma_f32_32x32x16_bf16(vfr, bb.v, o[db], 0, 0, 0);
        }
      }
      __builtin_amdgcn_s_setprio(0);
    }
    if (t + 1 < NT) __syncthreads();
  }
  float inv = 1.f / lsum;
#pragma unroll
  for (int db = 0; db < 4; ++db)
#pragma unroll
    for (int rg = 0; rg < 4; ++rg) {
      bf16x4 ov;
#pragma unroll
      for (int j = 0; j < 4; ++j) ov[j] = (__bf16)(o[db][rg * 4 + j] * inv);
      *(bf16x4*)(O + (size_t)qrow * D_ + h * HD_ + db * 32 + rg * 8 + g * 4) = ov;
    }
}

// ---------------------------------------------------------------------------
extern "C" void kernel_launch(void* const* d_in, const int* in_sizes, int n_in,
                              void* d_out, int out_size, void* d_ws, size_t ws_size,
                              hipStream_t stream) {
  const float* hidden = (const float*)d_in[0];
  const float* cosT   = (const float*)d_in[1];
  const float* sinT   = (const float*)d_in[2];
  const float* w_qkv  = (const float*)d_in[3];
  const float* w_out  = (const float*)d_in[4];
  float* out = (float*)d_out;
  char* ws = (char*)d_ws;

  __bf16* wT   = (__bf16*)ws;
  __bf16* hb   = (__bf16*)(ws + 100663296);
  __bf16* qkvb = (__bf16*)(ws + 100663296 + 25165824);
  __bf16* q_b  = (__bf16*)(ws + 100663296 + 25165824 + 33554432);
  __bf16* k_b  = q_b + (size_t)S_ * H_ * HD_;
  __bf16* vt_b = k_b + (size_t)S_ * KV_ * HD_;

  cvt_bf16<<<dim3(2048), dim3(256), 0, stream>>>(hidden, hb, (int)((size_t)S_ * D_ / 4));
  wtrans<<<dim3(NQK / 32, D_ / 64), dim3(256), 0, stream>>>(w_qkv, wT, D_, NQK);
  gemm_bt<__bf16, 256><<<dim3(NQK / 256, S_ / 256), dim3(512), 0, stream>>>(hb, wT, qkvb, S_, NQK, D_);
  rope_qk<<<dim3(S_), dim3(256), 0, stream>>>(qkvb, cosT, sinT, q_b, k_b);
  v_trans<<<dim3(S_ / 32, HD_ / 32, KV_), dim3(8, 32), 0, stream>>>(qkvb, vt_b);
  wtrans<<<dim3(D_ / 32, D_ / 64), dim3(256), 0, stream>>>(w_out, wT, D_, D_);
  attn<<<dim3(S_ / 128, H_), dim3(256), 0, stream>>>(q_b, k_b, vt_b, hb);
  gemm2_bt<float><<<dim3(D_ / 192, S_ / 128), dim3(512), 0, stream>>>(hb, wT, out, S_, D_, D_);
}